// Round 12
// baseline (777.654 us; speedup 1.0000x reference)
//
#include <hip/hip_runtime.h>

typedef unsigned short u16;
typedef __bf16 bf16x8 __attribute__((ext_vector_type(8)));
typedef float f32x4 __attribute__((ext_vector_type(4)));

#define B_SZ   4096
#define H_NUM  32
#define F_DIM  1024
#define NTOT   (H_NUM * F_DIM)   // 32768
#define N_CAT  8
#define CAT_D  16
#define N_CONT 24
#define LN_EPS 1e-5f
#define NSTRIP 128               // 256-col strips in the 256^2 GEMM

__device__ __forceinline__ u16 f2bf(float f) {
    unsigned int u = __builtin_bit_cast(unsigned int, f);
    unsigned int r = (u + 0x7FFFu + ((u >> 16) & 1u)) >> 16;
    return (u16)r;
}

__device__ __forceinline__ float bf2f(u16 v) {
    unsigned int u = ((unsigned int)v) << 16;
    return __builtin_bit_cast(float, u);
}

__device__ __forceinline__ void gl2lds16(const void* g, void* l) {
    __builtin_amdgcn_global_load_lds(
        (const __attribute__((address_space(1))) void*)g,
        (__attribute__((address_space(3))) void*)l,
        16, 0, 0);
}

__device__ __forceinline__ float wave_sum(float v) {
#pragma unroll
    for (int o = 32; o; o >>= 1) v += __shfl_xor(v, o);
    return v;
}

// ---------------- z f32 -> bf16 ----------------
__global__ __launch_bounds__(256) void zconv(const float* __restrict__ z,
                                             u16* __restrict__ zb) {
    int i = blockIdx.x * 256 + threadIdx.x;      // one float4 per thread
    float4 v = ((const float4*)z)[i];
    ushort4 o;
    o.x = f2bf(v.x); o.y = f2bf(v.y); o.z = f2bf(v.z); o.w = f2bf(v.w);
    ((ushort4*)zb)[i] = o;
}

// ---------------- W_proj [h][f][d] f32 -> Wt [h][d][f] bf16 ----------------
__global__ __launch_bounds__(256) void transpose_w(const float* __restrict__ W,
                                                   u16* __restrict__ Wt) {
    __shared__ u16 tile[64][72];
    const int h = blockIdx.z;
    const int f0 = blockIdx.x * 64;
    const int d0 = blockIdx.y * 64;
    const float* Wh = W + (size_t)h * F_DIM * F_DIM;
    u16* Wth = Wt + (size_t)h * F_DIM * F_DIM;
    const int t = threadIdx.x;

#pragma unroll
    for (int i = 0; i < 4; ++i) {
        int idx = i * 256 + t;        // 0..1023
        int fr = idx >> 4;            // 0..63
        int c4 = idx & 15;            // 0..15
        float4 v = *(const float4*)(Wh + (size_t)(f0 + fr) * F_DIM + d0 + c4 * 4);
        tile[fr][c4 * 4 + 0] = f2bf(v.x);
        tile[fr][c4 * 4 + 1] = f2bf(v.y);
        tile[fr][c4 * 4 + 2] = f2bf(v.z);
        tile[fr][c4 * 4 + 3] = f2bf(v.w);
    }
    __syncthreads();
#pragma unroll
    for (int i = 0; i < 2; ++i) {
        int idx = i * 256 + t;        // 0..511
        int dr = idx >> 3;            // 0..63
        int c8 = idx & 7;             // 0..7
        __attribute__((aligned(16))) u16 tmp[8];
#pragma unroll
        for (int j = 0; j < 8; ++j) tmp[j] = tile[c8 * 8 + j][dr];
        *(uint4*)(Wth + (size_t)(d0 + dr) * F_DIM + f0 + c8 * 8) = *(const uint4*)tmp;
    }
}

// ---------------- GEMM 256^2, 8 waves, 2-Ktile LDS dbuf, XOR-swizzled ----------------
// (unchanged from R9 — verified)
template <int BF>
__global__ __launch_bounds__(512, 2) void gemm256(const u16* __restrict__ A,
                                                  const u16* __restrict__ Bt,
                                                  const float* __restrict__ bproj,
                                                  u16* __restrict__ lat16,
                                                  float* __restrict__ latf,
                                                  float* __restrict__ psum,
                                                  float* __restrict__ psumsq) {
    extern __shared__ u16 dynlds[];
    const int t = threadIdx.x;
    const int wid = t >> 6;            // 0..7
    const int lane = t & 63;
    const int l16 = lane & 15;
    const int lk = lane >> 4;          // 0..3
    const int wm = wid >> 2;           // 0..1  (A half / 128-row block)
    const int wn = wid & 3;            // 0..3  (64-col block)

    const int wg = blockIdx.x;
    const int xcd = wg & 7;
    const int local = wg >> 3;         // 0..255
    const int m0 = (local & 15) * 256;
    const int n0 = ((xcd << 4) + (local >> 4)) * 256;

    f32x4 acc[8][4];
    const f32x4 zero = {0.f, 0.f, 0.f, 0.f};
#pragma unroll
    for (int m = 0; m < 8; ++m)
#pragma unroll
        for (int n = 0; n < 4; ++n) acc[m][n] = zero;

    auto stage = [&](int p, int ktn, int bn) {
        const char* srcbase = (p < 2) ? (const char*)A : (const char*)Bt;
        const int rowbase = (p < 2) ? (m0 + p * 128) : (n0 + (p - 2) * 128);
        u16* ldsbase = dynlds + bn * 32768 + (p >> 1) * 16384 + (p & 1) * 8192;
#pragma unroll
        for (int i = 0; i < 2; ++i) {
            int oo = i * 8192 + t * 16;                  // byte off in 16KB half
            int oos = oo ^ (((oo >> 7) & 7) << 4);       // pre-swizzled source
            int row = oo >> 7;
            int colb = oos & 127;
            gl2lds16(srcbase + (size_t)(rowbase + row) * 2048 + ktn * 128 + colb,
                     ldsbase + i * 4096 + (wid << 9));   // wave-uniform dest (u16 units)
        }
    };

#pragma unroll
    for (int p = 0; p < 4; ++p) stage(p, 0, 0);
    __syncthreads();

    const int swz = (l16 & 7) << 4;                      // read-side XOR (bytes)
    for (int kt = 0; kt < 16; ++kt) {
        const int buf = kt & 1;
        const char* aB = (const char*)(dynlds + buf * 32768 + wm * 8192);
        const char* bB = (const char*)(dynlds + buf * 32768 + 16384 + (wn >> 1) * 8192);
        bf16x8 bfr[4][2];
#pragma unroll
        for (int p = 0; p < 4; ++p) {
            if (kt < 15) stage(p, kt + 1, buf ^ 1);
            if (p == 0) {
#pragma unroll
                for (int nr = 0; nr < 4; ++nr)
#pragma unroll
                    for (int kk = 0; kk < 2; ++kk)
                        bfr[nr][kk] = *(const bf16x8*)(bB +
                            ((wn & 1) * 64 + nr * 16 + l16) * 128 +
                            ((kk * 64 + lk * 16) ^ swz));
            }
            bf16x8 afr[2][2];
#pragma unroll
            for (int mr = 0; mr < 2; ++mr)
#pragma unroll
                for (int kk = 0; kk < 2; ++kk)
                    afr[mr][kk] = *(const bf16x8*)(aB +
                        (p * 32 + mr * 16 + l16) * 128 +
                        ((kk * 64 + lk * 16) ^ swz));
            __builtin_amdgcn_s_setprio(1);
#pragma unroll
            for (int kk = 0; kk < 2; ++kk)
#pragma unroll
                for (int mr = 0; mr < 2; ++mr)
#pragma unroll
                    for (int nr = 0; nr < 4; ++nr)
                        acc[p * 2 + mr][nr] = __builtin_amdgcn_mfma_f32_16x16x32_bf16(
                            afr[mr][kk], bfr[nr][kk], acc[p * 2 + mr][nr], 0, 0, 0);
            __builtin_amdgcn_s_setprio(0);
        }
        __syncthreads();   // drain kt+1 stage loads; fence buf reuse
    }

    // ---- epilogue: bf16 latent store + LN partials (reuse dead buf0 LDS) ----
    float bias[4];
#pragma unroll
    for (int nr = 0; nr < 4; ++nr) bias[nr] = bproj[n0 + wn * 64 + nr * 16 + l16];

    float sm[8][4], s2[8][4];
#pragma unroll
    for (int mr = 0; mr < 8; ++mr)
#pragma unroll
        for (int j = 0; j < 4; ++j) { sm[mr][j] = 0.f; s2[mr][j] = 0.f; }

#pragma unroll
    for (int mr = 0; mr < 8; ++mr) {
#pragma unroll
        for (int j = 0; j < 4; ++j) {
            const int rowg = m0 + wm * 128 + mr * 16 + lk * 4 + j;
            size_t off = (size_t)rowg * NTOT + n0 + wn * 64 + l16;
#pragma unroll
            for (int nr = 0; nr < 4; ++nr) {
                float v = acc[mr][nr][j] + bias[nr];
                if (BF) lat16[off + nr * 16] = f2bf(v);
                else    latf[off + nr * 16] = v;
                sm[mr][j] += v;
                s2[mr][j] += v * v;
            }
        }
    }
#pragma unroll
    for (int o = 1; o < 16; o <<= 1) {
#pragma unroll
        for (int mr = 0; mr < 8; ++mr)
#pragma unroll
            for (int j = 0; j < 4; ++j) {
                sm[mr][j] += __shfl_xor(sm[mr][j], o);
                s2[mr][j] += __shfl_xor(s2[mr][j], o);
            }
    }
    float* sredf = (float*)dynlds;            // [4][256]  (aliases dead buf0)
    float* s2f   = sredf + 1024;              // [4][256]
    __syncthreads();
    if (l16 == 0) {
#pragma unroll
        for (int mr = 0; mr < 8; ++mr)
#pragma unroll
            for (int j = 0; j < 4; ++j) {
                int r = wm * 128 + mr * 16 + lk * 4 + j;
                sredf[wn * 256 + r] = sm[mr][j];
                s2f[wn * 256 + r] = s2[mr][j];
            }
    }
    __syncthreads();
    if (t < 256) {
        const int strip = n0 >> 8;
        float S = sredf[t] + sredf[256 + t] + sredf[512 + t] + sredf[768 + t];
        float S2 = s2f[t] + s2f[256 + t] + s2f[512 + t] + s2f[768 + t];
        psum[(size_t)strip * B_SZ + m0 + t] = S;
        psumsq[(size_t)strip * B_SZ + m0 + t] = S2;
    }
}

// ---------------- finalize LN stats from partials (psum layout [strip][b]) ----------------
__global__ __launch_bounds__(256) void ln_finalize(const float* __restrict__ psum,
                                                   const float* __restrict__ psumsq,
                                                   float* __restrict__ murs) {
    const int t = threadIdx.x;
    const int b0 = blockIdx.x * 64;
    const int tb = t & 63;            // which b
    const int tg = t >> 6;            // strip group 0..3
    float s = 0.f, s2 = 0.f;
    for (int sidx = tg; sidx < NSTRIP; sidx += 4) {
        s += psum[(size_t)sidx * B_SZ + b0 + tb];
        s2 += psumsq[(size_t)sidx * B_SZ + b0 + tb];
    }
    __shared__ float r1[4][64], r2[4][64];
    r1[tg][tb] = s;
    r2[tg][tb] = s2;
    __syncthreads();
    if (t < 64) {
        float S = r1[0][t] + r1[1][t] + r1[2][t] + r1[3][t];
        float S2 = r2[0][t] + r2[1][t] + r2[2][t] + r2[3][t];
        float m = S / (float)NTOT;
        float var = S2 / (float)NTOT - m * m;
        murs[b0 + t] = m;
        murs[B_SZ + b0 + t] = rsqrtf(var + LN_EPS);
    }
}

// ---------------- normalize + relu + heads: TWO blocks per b ----------------
// half 0: heads 0..15 (8 cat + 8 cont); half 1: heads 16..31 (16 cont).
// Phase 1: barrier-free stream (16 iters): load lat16, normalize, NT-store latent
//   (non-temporal so the 512MB write stream doesn't evict L3-resident lat16);
//   cat heads stage bf16 y to LDS, cont heads keep a per-thread partial.
// Phase 2: half 0 only: 8 cat GEMVs with float4 Wcat loads (cq=t&3, fg=t>>2);
//   batched cont wave-reduce. Phase 3: softmax / pcont finalize.
template <int BF>
__global__ __launch_bounds__(256) void headsI(const void* __restrict__ latin_,
                                              float* __restrict__ latout,
                                              const float* __restrict__ murs,
                                              const float* __restrict__ lnw,
                                              const float* __restrict__ lnb,
                                              const float* __restrict__ Wcat,
                                              const float* __restrict__ bcat,
                                              const float* __restrict__ Wcont,
                                              const float* __restrict__ bcont,
                                              float* __restrict__ pcat,
                                              float* __restrict__ pcont) {
    const int half = blockIdx.x;              // 0: h 0..15, 1: h 16..31
    const int b = blockIdx.y;
    const int t = threadIdx.x;
    const int lane = t & 63;
    const int w4 = t >> 6;                    // wave 0..3
    const float mu = murs[b];
    const float rs = murs[B_SZ + b];
    const ushort4* lin16 = (const ushort4*)((const u16*)latin_ + (size_t)b * NTOT);
    const float4*  linf  = (const float4*)((const float*)latin_ + (size_t)b * NTOT);
    f32x4* lout4 = (f32x4*)(latout + (size_t)b * NTOT);
    const float4* lnw4 = (const float4*)lnw;
    const float4* lnb4 = (const float4*)lnb;
    const float4* wcont4 = (const float4*)Wcont;

    __shared__ ushort4 sy16[N_CAT * 256];     // 8 cat heads' y, bf16 (16 KB; half 0)
    __shared__ float4 cred4[4][N_CAT][4];     // [wave][h][cq] partials (2 KB)
    __shared__ float nred[16][4];             // cont partials (local head idx)

    const int kbase = half << 4;
    float cp[16];

    // ---- phase 1: barrier-free stream over this half's 16 heads ----
#pragma unroll 4
    for (int kk = 0; kk < 16; ++kk) {
        const int k = kbase + kk;
        const int i = (k << 8) + t;
        float4 x;
        if (BF) {
            ushort4 xv = lin16[i];
            x.x = bf2f(xv.x); x.y = bf2f(xv.y); x.z = bf2f(xv.z); x.w = bf2f(xv.w);
        } else {
            x = linf[i];
        }
        float4 w = lnw4[i];
        float4 bv = lnb4[i];
        float4 yo;
        yo.x = fmaxf(0.f, (x.x - mu) * rs * w.x + bv.x);
        yo.y = fmaxf(0.f, (x.y - mu) * rs * w.y + bv.y);
        yo.z = fmaxf(0.f, (x.z - mu) * rs * w.z + bv.z);
        yo.w = fmaxf(0.f, (x.w - mu) * rs * w.w + bv.w);
        f32x4 yv = {yo.x, yo.y, yo.z, yo.w};
        __builtin_nontemporal_store(yv, lout4 + i);
        if (half == 0 && k < N_CAT) {
            ushort4 ys;
            ys.x = f2bf(yo.x); ys.y = f2bf(yo.y); ys.z = f2bf(yo.z); ys.w = f2bf(yo.w);
            sy16[i] = ys;                      // own slot, no race
            cp[kk] = 0.f;
        } else {
            float4 wv = wcont4[((k - N_CAT) << 8) + t];
            cp[kk] = yo.x * wv.x + yo.y * wv.y + yo.z * wv.z + yo.w * wv.w;
        }
    }
    __syncthreads();

    // ---- phase 2 ----
    if (half == 0) {
        // cat GEMVs: thread owns c-quad cq = t&3, f-range fg*16..fg*16+15
        const int cq = t & 3;
        const int fg = t >> 2;                // 0..63
        for (int k = 0; k < N_CAT; ++k) {
            const float4* Wc4 = (const float4*)(Wcat + (size_t)k * F_DIM * CAT_D);
            float4 a4 = {0.f, 0.f, 0.f, 0.f};
#pragma unroll
            for (int jq = 0; jq < 4; ++jq) {
                ushort4 yv = sy16[(k << 8) + fg * 4 + jq];
                float ys[4] = {bf2f(yv.x), bf2f(yv.y), bf2f(yv.z), bf2f(yv.w)};
#pragma unroll
                for (int r = 0; r < 4; ++r) {
                    int f = fg * 16 + jq * 4 + r;
                    float4 wv = Wc4[f * 4 + cq];
                    a4.x += ys[r] * wv.x;
                    a4.y += ys[r] * wv.y;
                    a4.z += ys[r] * wv.z;
                    a4.w += ys[r] * wv.w;
                }
            }
#pragma unroll
            for (int o = 4; o < 64; o <<= 1) {
                a4.x += __shfl_xor(a4.x, o);
                a4.y += __shfl_xor(a4.y, o);
                a4.z += __shfl_xor(a4.z, o);
                a4.w += __shfl_xor(a4.w, o);
            }
            if (lane < 4) cred4[w4][k][lane] = a4;   // lane == cq for lanes 0..3
        }
#pragma unroll
        for (int kk = 8; kk < 16; ++kk) {            // cont heads h=8..15 -> ci 0..7
            float v = wave_sum(cp[kk]);
            if (lane == 0) nred[kk - 8][w4] = v;
        }
    } else {
#pragma unroll
        for (int kk = 0; kk < 16; ++kk) {            // cont heads h=16..31 -> ci 8..23
            float v = wave_sum(cp[kk]);
            if (lane == 0) nred[kk][w4] = v;
        }
    }
    __syncthreads();

    // ---- phase 3: finalize ----
    if (half == 0) {
        if (t < 128) {                        // softmax: h = t>>4, c = t&15
            const int h = t >> 4, c = t & 15;
            float lg = bcat[h * CAT_D + c];
#pragma unroll
            for (int w = 0; w < 4; ++w)
                lg += ((const float*)cred4[w][h])[c];
            float mx = lg;
#pragma unroll
            for (int o = 8; o; o >>= 1) mx = fmaxf(mx, __shfl_xor(mx, o, 16));
            float e = __expf(lg - mx);
            float sm2 = e;
#pragma unroll
            for (int o = 8; o; o >>= 1) sm2 += __shfl_xor(sm2, o, 16);
            pcat[(size_t)b * (N_CAT * CAT_D) + t] = e / sm2;
        } else if (t >= 128 && t < 128 + 8) {
            const int ci = t - 128;           // 0..7
            pcont[(size_t)b * N_CONT + ci] =
                nred[ci][0] + nred[ci][1] + nred[ci][2] + nred[ci][3] + bcont[ci];
        }
    } else {
        if (t < 16) {
            const int ci = 8 + t;             // 8..23
            pcont[(size_t)b * N_CONT + ci] =
                nred[t][0] + nred[t][1] + nred[t][2] + nred[t][3] + bcont[ci];
        }
    }
}

extern "C" void kernel_launch(void* const* d_in, const int* in_sizes, int n_in,
                              void* d_out, int out_size, void* d_ws, size_t ws_size,
                              hipStream_t stream) {
    const float* z     = (const float*)d_in[0];
    // d_in[1] = edge (unused by reference computation)
    const float* Wp    = (const float*)d_in[2];
    const float* bp    = (const float*)d_in[3];
    const float* lnw   = (const float*)d_in[4];
    const float* lnb   = (const float*)d_in[5];
    const float* Wcat  = (const float*)d_in[6];
    const float* bcat  = (const float*)d_in[7];
    const float* Wcont = (const float*)d_in[8];
    const float* bcont = (const float*)d_in[9];

    float* out    = (float*)d_out;
    float* pcat   = out;                                   // [4096, 8, 16]
    float* pcont  = out + (size_t)B_SZ * N_CAT * CAT_D;    // [4096, 24, 1]
    float* latent = pcont + (size_t)B_SZ * N_CONT;         // [4096, 32, 1024]

    u16* zb     = (u16*)d_ws;                              // 8 MB
    u16* Wt     = zb + (size_t)B_SZ * F_DIM;               // 64 MB
    float* murs = (float*)(Wt + (size_t)NTOT * F_DIM);     // 32 KB
    float* psum   = murs + 2 * B_SZ;                       // [128][4096] 2 MB
    float* psumsq = psum + (size_t)B_SZ * NSTRIP;          // 2 MB
    u16* lat16  = (u16*)(psumsq + (size_t)B_SZ * NSTRIP);  // 256 MB (optional)

    const size_t need = (size_t)((char*)(lat16 + (size_t)B_SZ * NTOT) - (char*)d_ws);
    const bool usebf = ws_size >= need;

    const int LDSB = 131072;
    zconv<<<dim3(B_SZ * F_DIM / 1024), 256, 0, stream>>>(z, zb);
    transpose_w<<<dim3(16, 16, 32), 256, 0, stream>>>(Wp, Wt);
    if (usebf) {
        (void)hipFuncSetAttribute((const void*)gemm256<1>,
                                  hipFuncAttributeMaxDynamicSharedMemorySize, LDSB);
        gemm256<1><<<dim3(2048), 512, LDSB, stream>>>(zb, Wt, bp, lat16, nullptr,
                                                      psum, psumsq);
        ln_finalize<<<dim3(B_SZ / 64), 256, 0, stream>>>(psum, psumsq, murs);
        headsI<1><<<dim3(2, B_SZ), 256, 0, stream>>>(lat16, latent, murs, lnw, lnb,
                                                     Wcat, bcat, Wcont, bcont, pcat, pcont);
    } else {
        (void)hipFuncSetAttribute((const void*)gemm256<0>,
                                  hipFuncAttributeMaxDynamicSharedMemorySize, LDSB);
        gemm256<0><<<dim3(2048), 512, LDSB, stream>>>(zb, Wt, bp, nullptr, latent,
                                                      psum, psumsq);
        ln_finalize<<<dim3(B_SZ / 64), 256, 0, stream>>>(psum, psumsq, murs);
        headsI<0><<<dim3(2, B_SZ), 256, 0, stream>>>(latent, latent, murs, lnw, lnb,
                                                     Wcat, bcat, Wcont, bcont, pcat, pcont);
    }
}

// Round 13
// 704.516 us; speedup vs baseline: 1.1038x; 1.1038x over previous
//
#include <hip/hip_runtime.h>

typedef unsigned short u16;
typedef unsigned int u32;
typedef __bf16 bf16x8 __attribute__((ext_vector_type(8)));
typedef float f32x4 __attribute__((ext_vector_type(4)));

#define B_SZ   4096
#define H_NUM  32
#define F_DIM  1024
#define NTOT   (H_NUM * F_DIM)   // 32768
#define N_CAT  8
#define CAT_D  16
#define N_CONT 24
#define LN_EPS 1e-5f
#define NSTRIP 128               // 256-col strips in the 256^2 GEMM

__device__ __forceinline__ u16 f2bf(float f) {
    unsigned int u = __builtin_bit_cast(unsigned int, f);
    unsigned int r = (u + 0x7FFFu + ((u >> 16) & 1u)) >> 16;
    return (u16)r;
}

__device__ __forceinline__ float bf2f(u16 v) {
    unsigned int u = ((unsigned int)v) << 16;
    return __builtin_bit_cast(float, u);
}

__device__ __forceinline__ float bflo(u32 v) { return bf2f((u16)(v & 0xffffu)); }
__device__ __forceinline__ float bfhi(u32 v) { return bf2f((u16)(v >> 16)); }

__device__ __forceinline__ void gl2lds16(const void* g, void* l) {
    __builtin_amdgcn_global_load_lds(
        (const __attribute__((address_space(1))) void*)g,
        (__attribute__((address_space(3))) void*)l,
        16, 0, 0);
}

__device__ __forceinline__ float wave_sum(float v) {
#pragma unroll
    for (int o = 32; o; o >>= 1) v += __shfl_xor(v, o);
    return v;
}

// ---------------- z f32 -> bf16 ----------------
__global__ __launch_bounds__(256) void zconv(const float* __restrict__ z,
                                             u16* __restrict__ zb) {
    int i = blockIdx.x * 256 + threadIdx.x;      // one float4 per thread
    float4 v = ((const float4*)z)[i];
    ushort4 o;
    o.x = f2bf(v.x); o.y = f2bf(v.y); o.z = f2bf(v.z); o.w = f2bf(v.w);
    ((ushort4*)zb)[i] = o;
}

// ---------------- pack lnw/lnb interleaved bf16 + Wcont bf16 ----------------
// lnwb[i] (uint4): {w0|w1<<16, w2|w3<<16, b0|b1<<16, b2|b3<<16} for float4-group i.
// wc16[j] (ushort4): bf16 of Wcont float4-group j.
__global__ __launch_bounds__(256) void packln(const float* __restrict__ lnw,
                                              const float* __restrict__ lnb,
                                              const float* __restrict__ wcont,
                                              uint4* __restrict__ lnwb,
                                              ushort4* __restrict__ wc16) {
    int idx = blockIdx.x * 256 + threadIdx.x;
    if (idx < NTOT / 4) {
        float4 w = ((const float4*)lnw)[idx];
        float4 b = ((const float4*)lnb)[idx];
        uint4 o;
        o.x = (u32)f2bf(w.x) | ((u32)f2bf(w.y) << 16);
        o.y = (u32)f2bf(w.z) | ((u32)f2bf(w.w) << 16);
        o.z = (u32)f2bf(b.x) | ((u32)f2bf(b.y) << 16);
        o.w = (u32)f2bf(b.z) | ((u32)f2bf(b.w) << 16);
        lnwb[idx] = o;
    } else if (idx < NTOT / 4 + N_CONT * F_DIM / 4) {
        int j = idx - NTOT / 4;
        float4 v = ((const float4*)wcont)[j];
        ushort4 o;
        o.x = f2bf(v.x); o.y = f2bf(v.y); o.z = f2bf(v.z); o.w = f2bf(v.w);
        wc16[j] = o;
    }
}

// ---------------- W_proj [h][f][d] f32 -> Wt [h][d][f] bf16 ----------------
__global__ __launch_bounds__(256) void transpose_w(const float* __restrict__ W,
                                                   u16* __restrict__ Wt) {
    __shared__ u16 tile[64][72];
    const int h = blockIdx.z;
    const int f0 = blockIdx.x * 64;
    const int d0 = blockIdx.y * 64;
    const float* Wh = W + (size_t)h * F_DIM * F_DIM;
    u16* Wth = Wt + (size_t)h * F_DIM * F_DIM;
    const int t = threadIdx.x;

#pragma unroll
    for (int i = 0; i < 4; ++i) {
        int idx = i * 256 + t;        // 0..1023
        int fr = idx >> 4;            // 0..63
        int c4 = idx & 15;            // 0..15
        float4 v = *(const float4*)(Wh + (size_t)(f0 + fr) * F_DIM + d0 + c4 * 4);
        tile[fr][c4 * 4 + 0] = f2bf(v.x);
        tile[fr][c4 * 4 + 1] = f2bf(v.y);
        tile[fr][c4 * 4 + 2] = f2bf(v.z);
        tile[fr][c4 * 4 + 3] = f2bf(v.w);
    }
    __syncthreads();
#pragma unroll
    for (int i = 0; i < 2; ++i) {
        int idx = i * 256 + t;        // 0..511
        int dr = idx >> 3;            // 0..63
        int c8 = idx & 7;             // 0..7
        __attribute__((aligned(16))) u16 tmp[8];
#pragma unroll
        for (int j = 0; j < 8; ++j) tmp[j] = tile[c8 * 8 + j][dr];
        *(uint4*)(Wth + (size_t)(d0 + dr) * F_DIM + f0 + c8 * 8) = *(const uint4*)tmp;
    }
}

// ---------------- GEMM 256^2, 8 waves, 2-Ktile LDS dbuf, XOR-swizzled ----------------
// (unchanged from R9 — verified)
template <int BF>
__global__ __launch_bounds__(512, 2) void gemm256(const u16* __restrict__ A,
                                                  const u16* __restrict__ Bt,
                                                  const float* __restrict__ bproj,
                                                  u16* __restrict__ lat16,
                                                  float* __restrict__ latf,
                                                  float* __restrict__ psum,
                                                  float* __restrict__ psumsq) {
    extern __shared__ u16 dynlds[];
    const int t = threadIdx.x;
    const int wid = t >> 6;            // 0..7
    const int lane = t & 63;
    const int l16 = lane & 15;
    const int lk = lane >> 4;          // 0..3
    const int wm = wid >> 2;           // 0..1  (A half / 128-row block)
    const int wn = wid & 3;            // 0..3  (64-col block)

    const int wg = blockIdx.x;
    const int xcd = wg & 7;
    const int local = wg >> 3;         // 0..255
    const int m0 = (local & 15) * 256;
    const int n0 = ((xcd << 4) + (local >> 4)) * 256;

    f32x4 acc[8][4];
    const f32x4 zero = {0.f, 0.f, 0.f, 0.f};
#pragma unroll
    for (int m = 0; m < 8; ++m)
#pragma unroll
        for (int n = 0; n < 4; ++n) acc[m][n] = zero;

    auto stage = [&](int p, int ktn, int bn) {
        const char* srcbase = (p < 2) ? (const char*)A : (const char*)Bt;
        const int rowbase = (p < 2) ? (m0 + p * 128) : (n0 + (p - 2) * 128);
        u16* ldsbase = dynlds + bn * 32768 + (p >> 1) * 16384 + (p & 1) * 8192;
#pragma unroll
        for (int i = 0; i < 2; ++i) {
            int oo = i * 8192 + t * 16;                  // byte off in 16KB half
            int oos = oo ^ (((oo >> 7) & 7) << 4);       // pre-swizzled source
            int row = oo >> 7;
            int colb = oos & 127;
            gl2lds16(srcbase + (size_t)(rowbase + row) * 2048 + ktn * 128 + colb,
                     ldsbase + i * 4096 + (wid << 9));   // wave-uniform dest (u16 units)
        }
    };

#pragma unroll
    for (int p = 0; p < 4; ++p) stage(p, 0, 0);
    __syncthreads();

    const int swz = (l16 & 7) << 4;                      // read-side XOR (bytes)
    for (int kt = 0; kt < 16; ++kt) {
        const int buf = kt & 1;
        const char* aB = (const char*)(dynlds + buf * 32768 + wm * 8192);
        const char* bB = (const char*)(dynlds + buf * 32768 + 16384 + (wn >> 1) * 8192);
        bf16x8 bfr[4][2];
#pragma unroll
        for (int p = 0; p < 4; ++p) {
            if (kt < 15) stage(p, kt + 1, buf ^ 1);
            if (p == 0) {
#pragma unroll
                for (int nr = 0; nr < 4; ++nr)
#pragma unroll
                    for (int kk = 0; kk < 2; ++kk)
                        bfr[nr][kk] = *(const bf16x8*)(bB +
                            ((wn & 1) * 64 + nr * 16 + l16) * 128 +
                            ((kk * 64 + lk * 16) ^ swz));
            }
            bf16x8 afr[2][2];
#pragma unroll
            for (int mr = 0; mr < 2; ++mr)
#pragma unroll
                for (int kk = 0; kk < 2; ++kk)
                    afr[mr][kk] = *(const bf16x8*)(aB +
                        (p * 32 + mr * 16 + l16) * 128 +
                        ((kk * 64 + lk * 16) ^ swz));
            __builtin_amdgcn_s_setprio(1);
#pragma unroll
            for (int kk = 0; kk < 2; ++kk)
#pragma unroll
                for (int mr = 0; mr < 2; ++mr)
#pragma unroll
                    for (int nr = 0; nr < 4; ++nr)
                        acc[p * 2 + mr][nr] = __builtin_amdgcn_mfma_f32_16x16x32_bf16(
                            afr[mr][kk], bfr[nr][kk], acc[p * 2 + mr][nr], 0, 0, 0);
            __builtin_amdgcn_s_setprio(0);
        }
        __syncthreads();   // drain kt+1 stage loads; fence buf reuse
    }

    // ---- epilogue: bf16 latent store + LN partials (reuse dead buf0 LDS) ----
    float bias[4];
#pragma unroll
    for (int nr = 0; nr < 4; ++nr) bias[nr] = bproj[n0 + wn * 64 + nr * 16 + l16];

    float sm[8][4], s2[8][4];
#pragma unroll
    for (int mr = 0; mr < 8; ++mr)
#pragma unroll
        for (int j = 0; j < 4; ++j) { sm[mr][j] = 0.f; s2[mr][j] = 0.f; }

#pragma unroll
    for (int mr = 0; mr < 8; ++mr) {
#pragma unroll
        for (int j = 0; j < 4; ++j) {
            const int rowg = m0 + wm * 128 + mr * 16 + lk * 4 + j;
            size_t off = (size_t)rowg * NTOT + n0 + wn * 64 + l16;
#pragma unroll
            for (int nr = 0; nr < 4; ++nr) {
                float v = acc[mr][nr][j] + bias[nr];
                if (BF) lat16[off + nr * 16] = f2bf(v);
                else    latf[off + nr * 16] = v;
                sm[mr][j] += v;
                s2[mr][j] += v * v;
            }
        }
    }
#pragma unroll
    for (int o = 1; o < 16; o <<= 1) {
#pragma unroll
        for (int mr = 0; mr < 8; ++mr)
#pragma unroll
            for (int j = 0; j < 4; ++j) {
                sm[mr][j] += __shfl_xor(sm[mr][j], o);
                s2[mr][j] += __shfl_xor(s2[mr][j], o);
            }
    }
    float* sredf = (float*)dynlds;            // [4][256]  (aliases dead buf0)
    float* s2f   = sredf + 1024;              // [4][256]
    __syncthreads();
    if (l16 == 0) {
#pragma unroll
        for (int mr = 0; mr < 8; ++mr)
#pragma unroll
            for (int j = 0; j < 4; ++j) {
                int r = wm * 128 + mr * 16 + lk * 4 + j;
                sredf[wn * 256 + r] = sm[mr][j];
                s2f[wn * 256 + r] = s2[mr][j];
            }
    }
    __syncthreads();
    if (t < 256) {
        const int strip = n0 >> 8;
        float S = sredf[t] + sredf[256 + t] + sredf[512 + t] + sredf[768 + t];
        float S2 = s2f[t] + s2f[256 + t] + s2f[512 + t] + s2f[768 + t];
        psum[(size_t)strip * B_SZ + m0 + t] = S;
        psumsq[(size_t)strip * B_SZ + m0 + t] = S2;
    }
}

// ---------------- finalize LN stats from partials (psum layout [strip][b]) ----------------
__global__ __launch_bounds__(256) void ln_finalize(const float* __restrict__ psum,
                                                   const float* __restrict__ psumsq,
                                                   float* __restrict__ murs) {
    const int t = threadIdx.x;
    const int b0 = blockIdx.x * 64;
    const int tb = t & 63;            // which b
    const int tg = t >> 6;            // strip group 0..3
    float s = 0.f, s2 = 0.f;
    for (int sidx = tg; sidx < NSTRIP; sidx += 4) {
        s += psum[(size_t)sidx * B_SZ + b0 + tb];
        s2 += psumsq[(size_t)sidx * B_SZ + b0 + tb];
    }
    __shared__ float r1[4][64], r2[4][64];
    r1[tg][tb] = s;
    r2[tg][tb] = s2;
    __syncthreads();
    if (t < 64) {
        float S = r1[0][t] + r1[1][t] + r1[2][t] + r1[3][t];
        float S2 = r2[0][t] + r2[1][t] + r2[2][t] + r2[3][t];
        float m = S / (float)NTOT;
        float var = S2 / (float)NTOT - m * m;
        murs[b0 + t] = m;
        murs[B_SZ + b0 + t] = rsqrtf(var + LN_EPS);
    }
}

// ---------------- normalize + relu + heads: one 256-thread block per b ----------------
// R10 structure (known-good 360us) + packed bf16 LN params (32B loads/group vs 56B)
// + float4 Wcat GEMV in phase 2.
template <int BF>
__global__ __launch_bounds__(256) void headsJ(const void* __restrict__ latin_,
                                              float* __restrict__ latout,
                                              const float* __restrict__ murs,
                                              const uint4* __restrict__ lnwb,
                                              const ushort4* __restrict__ wc16,
                                              const float* __restrict__ Wcat,
                                              const float* __restrict__ bcat,
                                              const float* __restrict__ bcont,
                                              float* __restrict__ pcat,
                                              float* __restrict__ pcont) {
    const int b = blockIdx.x;
    const int t = threadIdx.x;
    const int lane = t & 63;
    const int w4 = t >> 6;                    // wave 0..3
    const float mu = murs[b];
    const float rs = murs[B_SZ + b];
    const ushort4* lin16 = (const ushort4*)((const u16*)latin_ + (size_t)b * NTOT);
    const float4*  linf  = (const float4*)((const float*)latin_ + (size_t)b * NTOT);
    float4* lout4 = (float4*)(latout + (size_t)b * NTOT);

    __shared__ ushort4 sy16[N_CAT * 256];     // 8 cat heads' y, bf16 (16 KB)
    __shared__ float4 cred4[4][N_CAT][4];     // [wave][h][cq] partials (2 KB)
    __shared__ float nred[N_CONT][4];         // cont partials

    float cp[N_CONT];

    // ---- phase 1a: cat heads — normalize, store, stage y (no barriers) ----
#pragma unroll 2
    for (int k = 0; k < N_CAT; ++k) {
        const int i = (k << 8) + t;
        float4 x;
        if (BF) {
            ushort4 xv = lin16[i];
            x.x = bf2f(xv.x); x.y = bf2f(xv.y); x.z = bf2f(xv.z); x.w = bf2f(xv.w);
        } else {
            x = linf[i];
        }
        uint4 wb = lnwb[i];
        float4 yo;
        yo.x = fmaxf(0.f, (x.x - mu) * rs * bflo(wb.x) + bflo(wb.z));
        yo.y = fmaxf(0.f, (x.y - mu) * rs * bfhi(wb.x) + bfhi(wb.z));
        yo.z = fmaxf(0.f, (x.z - mu) * rs * bflo(wb.y) + bflo(wb.w));
        yo.w = fmaxf(0.f, (x.w - mu) * rs * bfhi(wb.y) + bfhi(wb.w));
        lout4[i] = yo;
        ushort4 ys;
        ys.x = f2bf(yo.x); ys.y = f2bf(yo.y); ys.z = f2bf(yo.z); ys.w = f2bf(yo.w);
        sy16[i] = ys;                          // own slot, no race
    }

    // ---- phase 1b: cont heads — pure streaming, per-thread partial only ----
#pragma unroll 2
    for (int k = N_CAT; k < H_NUM; ++k) {
        const int i = (k << 8) + t;
        float4 x;
        if (BF) {
            ushort4 xv = lin16[i];
            x.x = bf2f(xv.x); x.y = bf2f(xv.y); x.z = bf2f(xv.z); x.w = bf2f(xv.w);
        } else {
            x = linf[i];
        }
        uint4 wb = lnwb[i];
        ushort4 wv = wc16[((k - N_CAT) << 8) + t];
        float4 yo;
        yo.x = fmaxf(0.f, (x.x - mu) * rs * bflo(wb.x) + bflo(wb.z));
        yo.y = fmaxf(0.f, (x.y - mu) * rs * bfhi(wb.x) + bfhi(wb.z));
        yo.z = fmaxf(0.f, (x.z - mu) * rs * bflo(wb.y) + bflo(wb.w));
        yo.w = fmaxf(0.f, (x.w - mu) * rs * bfhi(wb.y) + bfhi(wb.w));
        lout4[i] = yo;
        cp[k - N_CAT] = yo.x * bf2f(wv.x) + yo.y * bf2f(wv.y) +
                        yo.z * bf2f(wv.z) + yo.w * bf2f(wv.w);
    }
    __syncthreads();

    // ---- phase 2a: cat GEMVs from LDS, float4 Wcat (cq = t&3, fg = t>>2) ----
    const int cq = t & 3;
    const int fg = t >> 2;                    // 0..63
    for (int k = 0; k < N_CAT; ++k) {
        const float4* Wc4 = (const float4*)(Wcat + (size_t)k * F_DIM * CAT_D);
        float4 a4 = {0.f, 0.f, 0.f, 0.f};
#pragma unroll
        for (int jq = 0; jq < 4; ++jq) {
            ushort4 yv = sy16[(k << 8) + fg * 4 + jq];
            float ys[4] = {bf2f(yv.x), bf2f(yv.y), bf2f(yv.z), bf2f(yv.w)};
#pragma unroll
            for (int r = 0; r < 4; ++r) {
                int f = fg * 16 + jq * 4 + r;
                float4 wv = Wc4[f * 4 + cq];
                a4.x += ys[r] * wv.x;
                a4.y += ys[r] * wv.y;
                a4.z += ys[r] * wv.z;
                a4.w += ys[r] * wv.w;
            }
        }
#pragma unroll
        for (int o = 4; o < 64; o <<= 1) {
            a4.x += __shfl_xor(a4.x, o);
            a4.y += __shfl_xor(a4.y, o);
            a4.z += __shfl_xor(a4.z, o);
            a4.w += __shfl_xor(a4.w, o);
        }
        if (lane < 4) cred4[w4][k][lane] = a4;   // lane == cq for lanes 0..3
    }
    // ---- phase 2b: batched cont reduce ----
#pragma unroll
    for (int k = 0; k < N_CONT; ++k) {
        float v = wave_sum(cp[k]);
        if (lane == 0) nred[k][w4] = v;
    }
    __syncthreads();

    // ---- phase 3: finalize ----
    if (t < 128) {                            // cat softmax: h = t>>4, c = t&15
        const int h = t >> 4, c = t & 15;
        float lg = bcat[h * CAT_D + c];
#pragma unroll
        for (int w = 0; w < 4; ++w)
            lg += ((const float*)cred4[w][h])[c];
        float mx = lg;
#pragma unroll
        for (int o = 8; o; o >>= 1) mx = fmaxf(mx, __shfl_xor(mx, o, 16));
        float e = __expf(lg - mx);
        float sm2 = e;
#pragma unroll
        for (int o = 8; o; o >>= 1) sm2 += __shfl_xor(sm2, o, 16);
        pcat[(size_t)b * (N_CAT * CAT_D) + t] = e / sm2;
    } else if (t >= 128 && t < 128 + N_CONT) {
        const int ci = t - 128;
        pcont[(size_t)b * N_CONT + ci] =
            nred[ci][0] + nred[ci][1] + nred[ci][2] + nred[ci][3] + bcont[ci];
    }
}

extern "C" void kernel_launch(void* const* d_in, const int* in_sizes, int n_in,
                              void* d_out, int out_size, void* d_ws, size_t ws_size,
                              hipStream_t stream) {
    const float* z     = (const float*)d_in[0];
    // d_in[1] = edge (unused by reference computation)
    const float* Wp    = (const float*)d_in[2];
    const float* bp    = (const float*)d_in[3];
    const float* lnw   = (const float*)d_in[4];
    const float* lnb   = (const float*)d_in[5];
    const float* Wcat  = (const float*)d_in[6];
    const float* bcat  = (const float*)d_in[7];
    const float* Wcont = (const float*)d_in[8];
    const float* bcont = (const float*)d_in[9];

    float* out    = (float*)d_out;
    float* pcat   = out;                                   // [4096, 8, 16]
    float* pcont  = out + (size_t)B_SZ * N_CAT * CAT_D;    // [4096, 24, 1]
    float* latent = pcont + (size_t)B_SZ * N_CONT;         // [4096, 32, 1024]

    u16* zb     = (u16*)d_ws;                              // 8 MB
    u16* Wt     = zb + (size_t)B_SZ * F_DIM;               // 64 MB
    float* murs = (float*)(Wt + (size_t)NTOT * F_DIM);     // 32 KB
    float* psum   = murs + 2 * B_SZ;                       // [128][4096] 2 MB
    float* psumsq = psum + (size_t)B_SZ * NSTRIP;          // 2 MB
    uint4* lnwb = (uint4*)(psumsq + (size_t)B_SZ * NSTRIP);        // 128 KB
    ushort4* wc16 = (ushort4*)(lnwb + NTOT / 4);                   // 48 KB
    u16* lat16  = (u16*)(wc16 + N_CONT * F_DIM / 4);       // 256 MB (optional)

    const size_t need = (size_t)((char*)(lat16 + (size_t)B_SZ * NTOT) - (char*)d_ws);
    const bool usebf = ws_size >= need;

    const int LDSB = 131072;
    zconv<<<dim3(B_SZ * F_DIM / 1024), 256, 0, stream>>>(z, zb);
    packln<<<dim3((NTOT / 4 + N_CONT * F_DIM / 4 + 255) / 256), 256, 0, stream>>>(
        lnw, lnb, Wcont, lnwb, wc16);
    transpose_w<<<dim3(16, 16, 32), 256, 0, stream>>>(Wp, Wt);
    if (usebf) {
        (void)hipFuncSetAttribute((const void*)gemm256<1>,
                                  hipFuncAttributeMaxDynamicSharedMemorySize, LDSB);
        gemm256<1><<<dim3(2048), 512, LDSB, stream>>>(zb, Wt, bp, lat16, nullptr,
                                                      psum, psumsq);
        ln_finalize<<<dim3(B_SZ / 64), 256, 0, stream>>>(psum, psumsq, murs);
        headsJ<1><<<dim3(B_SZ), 256, 0, stream>>>(lat16, latent, murs, lnwb, wc16,
                                                  Wcat, bcat, bcont, pcat, pcont);
    } else {
        (void)hipFuncSetAttribute((const void*)gemm256<0>,
                                  hipFuncAttributeMaxDynamicSharedMemorySize, LDSB);
        gemm256<0><<<dim3(2048), 512, LDSB, stream>>>(zb, Wt, bp, nullptr, latent,
                                                      psum, psumsq);
        ln_finalize<<<dim3(B_SZ / 64), 256, 0, stream>>>(psum, psumsq, murs);
        headsJ<0><<<dim3(B_SZ), 256, 0, stream>>>(latent, latent, murs, lnwb, wc16,
                                                  Wcat, bcat, bcont, pcat, pcont);
    }
}

// Round 14
// 698.632 us; speedup vs baseline: 1.1131x; 1.0084x over previous
//
#include <hip/hip_runtime.h>

typedef unsigned short u16;
typedef unsigned int u32;
typedef __bf16 bf16x8 __attribute__((ext_vector_type(8)));
typedef float f32x4 __attribute__((ext_vector_type(4)));

#define B_SZ   4096
#define H_NUM  32
#define F_DIM  1024
#define NTOT   (H_NUM * F_DIM)   // 32768
#define N_CAT  8
#define CAT_D  16
#define N_CONT 24
#define LN_EPS 1e-5f
#define NSTRIP 128               // 256-col strips in the 256^2 GEMM

__device__ __forceinline__ u16 f2bf(float f) {
    unsigned int u = __builtin_bit_cast(unsigned int, f);
    unsigned int r = (u + 0x7FFFu + ((u >> 16) & 1u)) >> 16;
    return (u16)r;
}

__device__ __forceinline__ float bf2f(u16 v) {
    unsigned int u = ((unsigned int)v) << 16;
    return __builtin_bit_cast(float, u);
}

__device__ __forceinline__ float bflo(u32 v) { return bf2f((u16)(v & 0xffffu)); }
__device__ __forceinline__ float bfhi(u32 v) { return bf2f((u16)(v >> 16)); }

__device__ __forceinline__ void gl2lds16(const void* g, void* l) {
    __builtin_amdgcn_global_load_lds(
        (const __attribute__((address_space(1))) void*)g,
        (__attribute__((address_space(3))) void*)l,
        16, 0, 0);
}

__device__ __forceinline__ float wave_sum(float v) {
#pragma unroll
    for (int o = 32; o; o >>= 1) v += __shfl_xor(v, o);
    return v;
}

// ---------------- z f32 -> bf16 ----------------
__global__ __launch_bounds__(256) void zconv(const float* __restrict__ z,
                                             u16* __restrict__ zb) {
    int i = blockIdx.x * 256 + threadIdx.x;      // one float4 per thread
    float4 v = ((const float4*)z)[i];
    ushort4 o;
    o.x = f2bf(v.x); o.y = f2bf(v.y); o.z = f2bf(v.z); o.w = f2bf(v.w);
    ((ushort4*)zb)[i] = o;
}

// ---------------- pack lnw/lnb interleaved bf16 + Wcont bf16 ----------------
__global__ __launch_bounds__(256) void packln(const float* __restrict__ lnw,
                                              const float* __restrict__ lnb,
                                              const float* __restrict__ wcont,
                                              uint4* __restrict__ lnwb,
                                              ushort4* __restrict__ wc16) {
    int idx = blockIdx.x * 256 + threadIdx.x;
    if (idx < NTOT / 4) {
        float4 w = ((const float4*)lnw)[idx];
        float4 b = ((const float4*)lnb)[idx];
        uint4 o;
        o.x = (u32)f2bf(w.x) | ((u32)f2bf(w.y) << 16);
        o.y = (u32)f2bf(w.z) | ((u32)f2bf(w.w) << 16);
        o.z = (u32)f2bf(b.x) | ((u32)f2bf(b.y) << 16);
        o.w = (u32)f2bf(b.z) | ((u32)f2bf(b.w) << 16);
        lnwb[idx] = o;
    } else if (idx < NTOT / 4 + N_CONT * F_DIM / 4) {
        int j = idx - NTOT / 4;
        float4 v = ((const float4*)wcont)[j];
        ushort4 o;
        o.x = f2bf(v.x); o.y = f2bf(v.y); o.z = f2bf(v.z); o.w = f2bf(v.w);
        wc16[j] = o;
    }
}

// ---------------- W_proj [h][f][d] f32 -> Wt [h][d][f] bf16 ----------------
__global__ __launch_bounds__(256) void transpose_w(const float* __restrict__ W,
                                                   u16* __restrict__ Wt) {
    __shared__ u16 tile[64][72];
    const int h = blockIdx.z;
    const int f0 = blockIdx.x * 64;
    const int d0 = blockIdx.y * 64;
    const float* Wh = W + (size_t)h * F_DIM * F_DIM;
    u16* Wth = Wt + (size_t)h * F_DIM * F_DIM;
    const int t = threadIdx.x;

#pragma unroll
    for (int i = 0; i < 4; ++i) {
        int idx = i * 256 + t;        // 0..1023
        int fr = idx >> 4;            // 0..63
        int c4 = idx & 15;            // 0..15
        float4 v = *(const float4*)(Wh + (size_t)(f0 + fr) * F_DIM + d0 + c4 * 4);
        tile[fr][c4 * 4 + 0] = f2bf(v.x);
        tile[fr][c4 * 4 + 1] = f2bf(v.y);
        tile[fr][c4 * 4 + 2] = f2bf(v.z);
        tile[fr][c4 * 4 + 3] = f2bf(v.w);
    }
    __syncthreads();
#pragma unroll
    for (int i = 0; i < 2; ++i) {
        int idx = i * 256 + t;        // 0..511
        int dr = idx >> 3;            // 0..63
        int c8 = idx & 7;             // 0..7
        __attribute__((aligned(16))) u16 tmp[8];
#pragma unroll
        for (int j = 0; j < 8; ++j) tmp[j] = tile[c8 * 8 + j][dr];
        *(uint4*)(Wth + (size_t)(d0 + dr) * F_DIM + f0 + c8 * 8) = *(const uint4*)tmp;
    }
}

// ---------------- GEMM 256^2, 8 waves, 2-Ktile LDS dbuf, XOR-swizzled ----------------
// R13 change: ALL of kt+1's stage loads are issued BEFORE kt's compute phases, so
// each load gets the full K-tile of MFMA as latency cover before the end-of-kt
// vmcnt(0) drain (was: spread across phases; phase-3 loads had ~1 phase of cover).
template <int BF>
__global__ __launch_bounds__(512, 2) void gemm256(const u16* __restrict__ A,
                                                  const u16* __restrict__ Bt,
                                                  const float* __restrict__ bproj,
                                                  u16* __restrict__ lat16,
                                                  float* __restrict__ latf,
                                                  float* __restrict__ psum,
                                                  float* __restrict__ psumsq) {
    extern __shared__ u16 dynlds[];
    const int t = threadIdx.x;
    const int wid = t >> 6;            // 0..7
    const int lane = t & 63;
    const int l16 = lane & 15;
    const int lk = lane >> 4;          // 0..3
    const int wm = wid >> 2;           // 0..1  (A half / 128-row block)
    const int wn = wid & 3;            // 0..3  (64-col block)

    const int wg = blockIdx.x;
    const int xcd = wg & 7;
    const int local = wg >> 3;         // 0..255
    const int m0 = (local & 15) * 256;
    const int n0 = ((xcd << 4) + (local >> 4)) * 256;

    f32x4 acc[8][4];
    const f32x4 zero = {0.f, 0.f, 0.f, 0.f};
#pragma unroll
    for (int m = 0; m < 8; ++m)
#pragma unroll
        for (int n = 0; n < 4; ++n) acc[m][n] = zero;

    auto stage = [&](int p, int ktn, int bn) {
        const char* srcbase = (p < 2) ? (const char*)A : (const char*)Bt;
        const int rowbase = (p < 2) ? (m0 + p * 128) : (n0 + (p - 2) * 128);
        u16* ldsbase = dynlds + bn * 32768 + (p >> 1) * 16384 + (p & 1) * 8192;
#pragma unroll
        for (int i = 0; i < 2; ++i) {
            int oo = i * 8192 + t * 16;                  // byte off in 16KB half
            int oos = oo ^ (((oo >> 7) & 7) << 4);       // pre-swizzled source
            int row = oo >> 7;
            int colb = oos & 127;
            gl2lds16(srcbase + (size_t)(rowbase + row) * 2048 + ktn * 128 + colb,
                     ldsbase + i * 4096 + (wid << 9));   // wave-uniform dest (u16 units)
        }
    };

#pragma unroll
    for (int p = 0; p < 4; ++p) stage(p, 0, 0);
    __syncthreads();

    const int swz = (l16 & 7) << 4;                      // read-side XOR (bytes)
    for (int kt = 0; kt < 16; ++kt) {
        const int buf = kt & 1;
        const char* aB = (const char*)(dynlds + buf * 32768 + wm * 8192);
        const char* bB = (const char*)(dynlds + buf * 32768 + 16384 + (wn >> 1) * 8192);

        // issue ALL of kt+1's loads up front: full-K-tile compute cover
        if (kt < 15) {
#pragma unroll
            for (int p = 0; p < 4; ++p) stage(p, kt + 1, buf ^ 1);
        }

        bf16x8 bfr[4][2];
#pragma unroll
        for (int p = 0; p < 4; ++p) {
            if (p == 0) {
#pragma unroll
                for (int nr = 0; nr < 4; ++nr)
#pragma unroll
                    for (int kk = 0; kk < 2; ++kk)
                        bfr[nr][kk] = *(const bf16x8*)(bB +
                            ((wn & 1) * 64 + nr * 16 + l16) * 128 +
                            ((kk * 64 + lk * 16) ^ swz));
            }
            bf16x8 afr[2][2];
#pragma unroll
            for (int mr = 0; mr < 2; ++mr)
#pragma unroll
                for (int kk = 0; kk < 2; ++kk)
                    afr[mr][kk] = *(const bf16x8*)(aB +
                        (p * 32 + mr * 16 + l16) * 128 +
                        ((kk * 64 + lk * 16) ^ swz));
            __builtin_amdgcn_s_setprio(1);
#pragma unroll
            for (int kk = 0; kk < 2; ++kk)
#pragma unroll
                for (int mr = 0; mr < 2; ++mr)
#pragma unroll
                    for (int nr = 0; nr < 4; ++nr)
                        acc[p * 2 + mr][nr] = __builtin_amdgcn_mfma_f32_16x16x32_bf16(
                            afr[mr][kk], bfr[nr][kk], acc[p * 2 + mr][nr], 0, 0, 0);
            __builtin_amdgcn_s_setprio(0);
        }
        __syncthreads();   // drain kt+1 stage loads; fence buf reuse
    }

    // ---- epilogue: bf16 latent store + LN partials (reuse dead buf0 LDS) ----
    float bias[4];
#pragma unroll
    for (int nr = 0; nr < 4; ++nr) bias[nr] = bproj[n0 + wn * 64 + nr * 16 + l16];

    float sm[8][4], s2[8][4];
#pragma unroll
    for (int mr = 0; mr < 8; ++mr)
#pragma unroll
        for (int j = 0; j < 4; ++j) { sm[mr][j] = 0.f; s2[mr][j] = 0.f; }

#pragma unroll
    for (int mr = 0; mr < 8; ++mr) {
#pragma unroll
        for (int j = 0; j < 4; ++j) {
            const int rowg = m0 + wm * 128 + mr * 16 + lk * 4 + j;
            size_t off = (size_t)rowg * NTOT + n0 + wn * 64 + l16;
#pragma unroll
            for (int nr = 0; nr < 4; ++nr) {
                float v = acc[mr][nr][j] + bias[nr];
                if (BF) lat16[off + nr * 16] = f2bf(v);
                else    latf[off + nr * 16] = v;
                sm[mr][j] += v;
                s2[mr][j] += v * v;
            }
        }
    }
#pragma unroll
    for (int o = 1; o < 16; o <<= 1) {
#pragma unroll
        for (int mr = 0; mr < 8; ++mr)
#pragma unroll
            for (int j = 0; j < 4; ++j) {
                sm[mr][j] += __shfl_xor(sm[mr][j], o);
                s2[mr][j] += __shfl_xor(s2[mr][j], o);
            }
    }
    float* sredf = (float*)dynlds;            // [4][256]  (aliases dead buf0)
    float* s2f   = sredf + 1024;              // [4][256]
    __syncthreads();
    if (l16 == 0) {
#pragma unroll
        for (int mr = 0; mr < 8; ++mr)
#pragma unroll
            for (int j = 0; j < 4; ++j) {
                int r = wm * 128 + mr * 16 + lk * 4 + j;
                sredf[wn * 256 + r] = sm[mr][j];
                s2f[wn * 256 + r] = s2[mr][j];
            }
    }
    __syncthreads();
    if (t < 256) {
        const int strip = n0 >> 8;
        float S = sredf[t] + sredf[256 + t] + sredf[512 + t] + sredf[768 + t];
        float S2 = s2f[t] + s2f[256 + t] + s2f[512 + t] + s2f[768 + t];
        psum[(size_t)strip * B_SZ + m0 + t] = S;
        psumsq[(size_t)strip * B_SZ + m0 + t] = S2;
    }
}

// ---------------- finalize LN stats from partials (psum layout [strip][b]) ----------------
__global__ __launch_bounds__(256) void ln_finalize(const float* __restrict__ psum,
                                                   const float* __restrict__ psumsq,
                                                   float* __restrict__ murs) {
    const int t = threadIdx.x;
    const int b0 = blockIdx.x * 64;
    const int tb = t & 63;            // which b
    const int tg = t >> 6;            // strip group 0..3
    float s = 0.f, s2 = 0.f;
    for (int sidx = tg; sidx < NSTRIP; sidx += 4) {
        s += psum[(size_t)sidx * B_SZ + b0 + tb];
        s2 += psumsq[(size_t)sidx * B_SZ + b0 + tb];
    }
    __shared__ float r1[4][64], r2[4][64];
    r1[tg][tb] = s;
    r2[tg][tb] = s2;
    __syncthreads();
    if (t < 64) {
        float S = r1[0][t] + r1[1][t] + r1[2][t] + r1[3][t];
        float S2 = r2[0][t] + r2[1][t] + r2[2][t] + r2[3][t];
        float m = S / (float)NTOT;
        float var = S2 / (float)NTOT - m * m;
        murs[b0 + t] = m;
        murs[B_SZ + b0 + t] = rsqrtf(var + LN_EPS);
    }
}

// ---------------- normalize + relu + heads: one 256-thread block per b ----------------
// (unchanged from R13 — verified)
template <int BF>
__global__ __launch_bounds__(256) void headsJ(const void* __restrict__ latin_,
                                              float* __restrict__ latout,
                                              const float* __restrict__ murs,
                                              const uint4* __restrict__ lnwb,
                                              const ushort4* __restrict__ wc16,
                                              const float* __restrict__ Wcat,
                                              const float* __restrict__ bcat,
                                              const float* __restrict__ bcont,
                                              float* __restrict__ pcat,
                                              float* __restrict__ pcont) {
    const int b = blockIdx.x;
    const int t = threadIdx.x;
    const int lane = t & 63;
    const int w4 = t >> 6;                    // wave 0..3
    const float mu = murs[b];
    const float rs = murs[B_SZ + b];
    const ushort4* lin16 = (const ushort4*)((const u16*)latin_ + (size_t)b * NTOT);
    const float4*  linf  = (const float4*)((const float*)latin_ + (size_t)b * NTOT);
    float4* lout4 = (float4*)(latout + (size_t)b * NTOT);

    __shared__ ushort4 sy16[N_CAT * 256];     // 8 cat heads' y, bf16 (16 KB)
    __shared__ float4 cred4[4][N_CAT][4];     // [wave][h][cq] partials (2 KB)
    __shared__ float nred[N_CONT][4];         // cont partials

    float cp[N_CONT];

    // ---- phase 1a: cat heads — normalize, store, stage y (no barriers) ----
#pragma unroll 2
    for (int k = 0; k < N_CAT; ++k) {
        const int i = (k << 8) + t;
        float4 x;
        if (BF) {
            ushort4 xv = lin16[i];
            x.x = bf2f(xv.x); x.y = bf2f(xv.y); x.z = bf2f(xv.z); x.w = bf2f(xv.w);
        } else {
            x = linf[i];
        }
        uint4 wb = lnwb[i];
        float4 yo;
        yo.x = fmaxf(0.f, (x.x - mu) * rs * bflo(wb.x) + bflo(wb.z));
        yo.y = fmaxf(0.f, (x.y - mu) * rs * bfhi(wb.x) + bfhi(wb.z));
        yo.z = fmaxf(0.f, (x.z - mu) * rs * bflo(wb.y) + bflo(wb.w));
        yo.w = fmaxf(0.f, (x.w - mu) * rs * bfhi(wb.y) + bfhi(wb.w));
        lout4[i] = yo;
        ushort4 ys;
        ys.x = f2bf(yo.x); ys.y = f2bf(yo.y); ys.z = f2bf(yo.z); ys.w = f2bf(yo.w);
        sy16[i] = ys;                          // own slot, no race
    }

    // ---- phase 1b: cont heads — pure streaming, per-thread partial only ----
#pragma unroll 2
    for (int k = N_CAT; k < H_NUM; ++k) {
        const int i = (k << 8) + t;
        float4 x;
        if (BF) {
            ushort4 xv = lin16[i];
            x.x = bf2f(xv.x); x.y = bf2f(xv.y); x.z = bf2f(xv.z); x.w = bf2f(xv.w);
        } else {
            x = linf[i];
        }
        uint4 wb = lnwb[i];
        ushort4 wv = wc16[((k - N_CAT) << 8) + t];
        float4 yo;
        yo.x = fmaxf(0.f, (x.x - mu) * rs * bflo(wb.x) + bflo(wb.z));
        yo.y = fmaxf(0.f, (x.y - mu) * rs * bfhi(wb.x) + bfhi(wb.z));
        yo.z = fmaxf(0.f, (x.z - mu) * rs * bflo(wb.y) + bflo(wb.w));
        yo.w = fmaxf(0.f, (x.w - mu) * rs * bfhi(wb.y) + bfhi(wb.w));
        lout4[i] = yo;
        cp[k - N_CAT] = yo.x * bf2f(wv.x) + yo.y * bf2f(wv.y) +
                        yo.z * bf2f(wv.z) + yo.w * bf2f(wv.w);
    }
    __syncthreads();

    // ---- phase 2a: cat GEMVs from LDS, float4 Wcat (cq = t&3, fg = t>>2) ----
    const int cq = t & 3;
    const int fg = t >> 2;                    // 0..63
    for (int k = 0; k < N_CAT; ++k) {
        const float4* Wc4 = (const float4*)(Wcat + (size_t)k * F_DIM * CAT_D);
        float4 a4 = {0.f, 0.f, 0.f, 0.f};
#pragma unroll
        for (int jq = 0; jq < 4; ++jq) {
            ushort4 yv = sy16[(k << 8) + fg * 4 + jq];
            float ys[4] = {bf2f(yv.x), bf2f(yv.y), bf2f(yv.z), bf2f(yv.w)};
#pragma unroll
            for (int r = 0; r < 4; ++r) {
                int f = fg * 16 + jq * 4 + r;
                float4 wv = Wc4[f * 4 + cq];
                a4.x += ys[r] * wv.x;
                a4.y += ys[r] * wv.y;
                a4.z += ys[r] * wv.z;
                a4.w += ys[r] * wv.w;
            }
        }
#pragma unroll
        for (int o = 4; o < 64; o <<= 1) {
            a4.x += __shfl_xor(a4.x, o);
            a4.y += __shfl_xor(a4.y, o);
            a4.z += __shfl_xor(a4.z, o);
            a4.w += __shfl_xor(a4.w, o);
        }
        if (lane < 4) cred4[w4][k][lane] = a4;   // lane == cq for lanes 0..3
    }
    // ---- phase 2b: batched cont reduce ----
#pragma unroll
    for (int k = 0; k < N_CONT; ++k) {
        float v = wave_sum(cp[k]);
        if (lane == 0) nred[k][w4] = v;
    }
    __syncthreads();

    // ---- phase 3: finalize ----
    if (t < 128) {                            // cat softmax: h = t>>4, c = t&15
        const int h = t >> 4, c = t & 15;
        float lg = bcat[h * CAT_D + c];
#pragma unroll
        for (int w = 0; w < 4; ++w)
            lg += ((const float*)cred4[w][h])[c];
        float mx = lg;
#pragma unroll
        for (int o = 8; o; o >>= 1) mx = fmaxf(mx, __shfl_xor(mx, o, 16));
        float e = __expf(lg - mx);
        float sm2 = e;
#pragma unroll
        for (int o = 8; o; o >>= 1) sm2 += __shfl_xor(sm2, o, 16);
        pcat[(size_t)b * (N_CAT * CAT_D) + t] = e / sm2;
    } else if (t >= 128 && t < 128 + N_CONT) {
        const int ci = t - 128;
        pcont[(size_t)b * N_CONT + ci] =
            nred[ci][0] + nred[ci][1] + nred[ci][2] + nred[ci][3] + bcont[ci];
    }
}

extern "C" void kernel_launch(void* const* d_in, const int* in_sizes, int n_in,
                              void* d_out, int out_size, void* d_ws, size_t ws_size,
                              hipStream_t stream) {
    const float* z     = (const float*)d_in[0];
    // d_in[1] = edge (unused by reference computation)
    const float* Wp    = (const float*)d_in[2];
    const float* bp    = (const float*)d_in[3];
    const float* lnw   = (const float*)d_in[4];
    const float* lnb   = (const float*)d_in[5];
    const float* Wcat  = (const float*)d_in[6];
    const float* bcat  = (const float*)d_in[7];
    const float* Wcont = (const float*)d_in[8];
    const float* bcont = (const float*)d_in[9];

    float* out    = (float*)d_out;
    float* pcat   = out;                                   // [4096, 8, 16]
    float* pcont  = out + (size_t)B_SZ * N_CAT * CAT_D;    // [4096, 24, 1]
    float* latent = pcont + (size_t)B_SZ * N_CONT;         // [4096, 32, 1024]

    u16* zb     = (u16*)d_ws;                              // 8 MB
    u16* Wt     = zb + (size_t)B_SZ * F_DIM;               // 64 MB
    float* murs = (float*)(Wt + (size_t)NTOT * F_DIM);     // 32 KB
    float* psum   = murs + 2 * B_SZ;                       // [128][4096] 2 MB
    float* psumsq = psum + (size_t)B_SZ * NSTRIP;          // 2 MB
    uint4* lnwb = (uint4*)(psumsq + (size_t)B_SZ * NSTRIP);        // 128 KB
    ushort4* wc16 = (ushort4*)(lnwb + NTOT / 4);                   // 48 KB
    u16* lat16  = (u16*)(wc16 + N_CONT * F_DIM / 4);       // 256 MB (optional)

    const size_t need = (size_t)((char*)(lat16 + (size_t)B_SZ * NTOT) - (char*)d_ws);
    const bool usebf = ws_size >= need;

    const int LDSB = 131072;
    zconv<<<dim3(B_SZ * F_DIM / 1024), 256, 0, stream>>>(z, zb);
    packln<<<dim3((NTOT / 4 + N_CONT * F_DIM / 4 + 255) / 256), 256, 0, stream>>>(
        lnw, lnb, Wcont, lnwb, wc16);
    transpose_w<<<dim3(16, 16, 32), 256, 0, stream>>>(Wp, Wt);
    if (usebf) {
        (void)hipFuncSetAttribute((const void*)gemm256<1>,
                                  hipFuncAttributeMaxDynamicSharedMemorySize, LDSB);
        gemm256<1><<<dim3(2048), 512, LDSB, stream>>>(zb, Wt, bp, lat16, nullptr,
                                                      psum, psumsq);
        ln_finalize<<<dim3(B_SZ / 64), 256, 0, stream>>>(psum, psumsq, murs);
        headsJ<1><<<dim3(B_SZ), 256, 0, stream>>>(lat16, latent, murs, lnwb, wc16,
                                                  Wcat, bcat, bcont, pcat, pcont);
    } else {
        (void)hipFuncSetAttribute((const void*)gemm256<0>,
                                  hipFuncAttributeMaxDynamicSharedMemorySize, LDSB);
        gemm256<0><<<dim3(2048), 512, LDSB, stream>>>(zb, Wt, bp, nullptr, latent,
                                                      psum, psumsq);
        ln_finalize<<<dim3(B_SZ / 64), 256, 0, stream>>>(psum, psumsq, murs);
        headsJ<0><<<dim3(B_SZ), 256, 0, stream>>>(latent, latent, murs, lnwb, wc16,
                                                  Wcat, bcat, bcont, pcat, pcont);
    }
}